// Round 1
// baseline (606.911 us; speedup 1.0000x reference)
//
#include <hip/hip_runtime.h>
#include <hip/hip_bf16.h>

// Problem constants
#define B_   16
#define C_   64
#define G_   256
#define P_   4096
#define W_   1024
#define H_   256
#define WQ_  256
#define M_   (B_ * P_)   // 65536 flattened (b,p) rows

// ---------------------------------------------------------------------------
// Kernel 1: prep — c = cx@Wc+bc, g = gx@Wg+bg, base = c@W1c + g@W1g + b1
// grid = B_ blocks, 256 threads
// ---------------------------------------------------------------------------
__global__ __launch_bounds__(256) void prep_kernel(
    const float* __restrict__ cx, const float* __restrict__ gx,
    const float* __restrict__ Wc, const float* __restrict__ bc,
    const float* __restrict__ Wg, const float* __restrict__ bg,
    const float* __restrict__ W1, const float* __restrict__ b1,
    float* __restrict__ base_out)
{
    const int b = blockIdx.x;
    const int t = threadIdx.x;
    __shared__ float cxl[C_], gxl[G_], cl[C_], gl[G_];

    if (t < C_) cxl[t] = cx[b * C_ + t];
    gxl[t] = gx[b * G_ + t];
    __syncthreads();

    if (t < C_) {
        float acc = bc[t];
        #pragma unroll 4
        for (int i = 0; i < C_; ++i) acc += cxl[i] * Wc[i * C_ + t];
        cl[t] = acc;
    }
    {
        float acc = bg[t];
        #pragma unroll 4
        for (int i = 0; i < G_; ++i) acc += gxl[i] * Wg[i * G_ + t];
        gl[t] = acc;
    }
    __syncthreads();

    float acc = b1[t];
    #pragma unroll 4
    for (int i = 0; i < C_; ++i) acc += cl[i] * W1[i * H_ + t];
    #pragma unroll 4
    for (int i = 0; i < G_; ++i) acc += gl[i] * W1[(C_ + i) * H_ + t];
    base_out[b * H_ + t] = acc;
}

// ---------------------------------------------------------------------------
// Kernel 2: w GEMM — w[row][q] = sum_k wx[row][k]*Ww[k][q] + bw[q]
// M=65536, K=1024, N=256.  BM=64, BN=256(all), BK=16. 256 thr, 8x8 reg tile.
// grid = M_/64 = 1024 blocks.
// ---------------------------------------------------------------------------
__global__ __launch_bounds__(256) void gemm_w_kernel(
    const float* __restrict__ A,     // wx  (M x 1024)
    const float* __restrict__ Bm,    // Ww  (1024 x 256)
    const float* __restrict__ bw,    // 256
    float* __restrict__ Cout)        // w   (M x 256)
{
    const int K = W_;
    __shared__ float As[16][68];     // [kk][row], row-stride 68*4=272B (16B-aligned)
    __shared__ float Bs[16][260];    // [kk][col], row-stride 1040B (16B-aligned)

    const int t    = threadIdx.x;
    const int row0 = blockIdx.x * 64;
    const int ty   = t >> 5;         // 0..7  -> rows ty*8..+8
    const int tx   = t & 31;         // 0..31 -> cols tx*8..+8

    float acc[8][8];
    #pragma unroll
    for (int i = 0; i < 8; ++i)
        #pragma unroll
        for (int j = 0; j < 8; ++j) acc[i][j] = 0.f;

    const int ar = t >> 2;           // 0..63
    const int ak = (t & 3) << 2;     // 0,4,8,12
    const int bk = t >> 6;           // 0..3
    const int bc2 = (t & 63) << 2;   // 0..252

    for (int k0 = 0; k0 < K; k0 += 16) {
        // A tile: 64 rows x 16 k
        float4 av = *(const float4*)(A + (size_t)(row0 + ar) * K + k0 + ak);
        As[ak + 0][ar] = av.x; As[ak + 1][ar] = av.y;
        As[ak + 2][ar] = av.z; As[ak + 3][ar] = av.w;
        // B tile: 16 k x 256 cols
        #pragma unroll
        for (int i = 0; i < 4; ++i) {
            float4 bv = *(const float4*)(Bm + (size_t)(k0 + bk + i * 4) * WQ_ + bc2);
            Bs[bk + i * 4][bc2 + 0] = bv.x; Bs[bk + i * 4][bc2 + 1] = bv.y;
            Bs[bk + i * 4][bc2 + 2] = bv.z; Bs[bk + i * 4][bc2 + 3] = bv.w;
        }
        __syncthreads();
        #pragma unroll
        for (int kk = 0; kk < 16; ++kk) {
            float a[8], bb[8];
            *(float4*)&a[0]  = *(const float4*)&As[kk][ty * 8];
            *(float4*)&a[4]  = *(const float4*)&As[kk][ty * 8 + 4];
            *(float4*)&bb[0] = *(const float4*)&Bs[kk][tx * 8];
            *(float4*)&bb[4] = *(const float4*)&Bs[kk][tx * 8 + 4];
            #pragma unroll
            for (int i = 0; i < 8; ++i)
                #pragma unroll
                for (int j = 0; j < 8; ++j)
                    acc[i][j] += a[i] * bb[j];
        }
        __syncthreads();
    }

    #pragma unroll
    for (int i = 0; i < 8; ++i) {
        const size_t r = (size_t)(row0 + ty * 8 + i);
        #pragma unroll
        for (int j = 0; j < 8; j += 4) {
            float4 v;
            v.x = acc[i][j + 0] + bw[tx * 8 + j + 0];
            v.y = acc[i][j + 1] + bw[tx * 8 + j + 1];
            v.z = acc[i][j + 2] + bw[tx * 8 + j + 2];
            v.w = acc[i][j + 3] + bw[tx * 8 + j + 3];
            *(float4*)(Cout + r * WQ_ + tx * 8 + j) = v;
        }
    }
}

// ---------------------------------------------------------------------------
// Kernel 3: scores GEMM — h = relu(base[b] + w @ W1w); scores = h @ W2 (+b2)
// A = w (M x 256), B = W1 rows [C+G .. D) (256 x 256), K=256.
// Same tiling as kernel 2; epilogue does relu + dot(W2) + half-wave reduce.
// grid = M_/64 = 1024 blocks.
// ---------------------------------------------------------------------------
__global__ __launch_bounds__(256) void gemm_scores_kernel(
    const float* __restrict__ A,      // w (M x 256)
    const float* __restrict__ W1w,    // W1 + (C_+G_)*H_ (256 x 256)
    const float* __restrict__ base_,  // B_ x 256
    const float* __restrict__ W2,     // 256
    const float* __restrict__ b2,     // 1
    float* __restrict__ scores)       // M
{
    const int K = H_;  // 256
    __shared__ float As[16][68];
    __shared__ float Bs[16][260];

    const int t    = threadIdx.x;
    const int row0 = blockIdx.x * 64;
    const int b    = row0 >> 12;      // row0 / 4096 (uniform: 4096 % 64 == 0)
    const int ty   = t >> 5;
    const int tx   = t & 31;

    float acc[8][8];
    #pragma unroll
    for (int i = 0; i < 8; ++i)
        #pragma unroll
        for (int j = 0; j < 8; ++j) acc[i][j] = 0.f;

    const int ar = t >> 2;
    const int ak = (t & 3) << 2;
    const int bk = t >> 6;
    const int bc2 = (t & 63) << 2;

    for (int k0 = 0; k0 < K; k0 += 16) {
        float4 av = *(const float4*)(A + (size_t)(row0 + ar) * K + k0 + ak);
        As[ak + 0][ar] = av.x; As[ak + 1][ar] = av.y;
        As[ak + 2][ar] = av.z; As[ak + 3][ar] = av.w;
        #pragma unroll
        for (int i = 0; i < 4; ++i) {
            float4 bv = *(const float4*)(W1w + (size_t)(k0 + bk + i * 4) * H_ + bc2);
            Bs[bk + i * 4][bc2 + 0] = bv.x; Bs[bk + i * 4][bc2 + 1] = bv.y;
            Bs[bk + i * 4][bc2 + 2] = bv.z; Bs[bk + i * 4][bc2 + 3] = bv.w;
        }
        __syncthreads();
        #pragma unroll
        for (int kk = 0; kk < 16; ++kk) {
            float a[8], bb[8];
            *(float4*)&a[0]  = *(const float4*)&As[kk][ty * 8];
            *(float4*)&a[4]  = *(const float4*)&As[kk][ty * 8 + 4];
            *(float4*)&bb[0] = *(const float4*)&Bs[kk][tx * 8];
            *(float4*)&bb[4] = *(const float4*)&Bs[kk][tx * 8 + 4];
            #pragma unroll
            for (int i = 0; i < 8; ++i)
                #pragma unroll
                for (int j = 0; j < 8; ++j)
                    acc[i][j] += a[i] * bb[j];
        }
        __syncthreads();
    }

    // epilogue: relu(base + acc) dot W2, reduce over tx (32 lanes per half-wave)
    float basev[8], w2v[8];
    #pragma unroll
    for (int j = 0; j < 8; ++j) {
        basev[j] = base_[b * H_ + tx * 8 + j];
        w2v[j]   = W2[tx * 8 + j];
    }
    const float b2v = b2[0];
    #pragma unroll
    for (int i = 0; i < 8; ++i) {
        float sv = 0.f;
        #pragma unroll
        for (int j = 0; j < 8; ++j) {
            float h = acc[i][j] + basev[j];
            h = fmaxf(h, 0.f);
            sv += h * w2v[j];
        }
        #pragma unroll
        for (int d = 1; d < 32; d <<= 1) sv += __shfl_xor(sv, d, 64);
        if (tx == 0) scores[row0 + ty * 8 + i] = sv + b2v;
    }
}

// ---------------------------------------------------------------------------
// Kernel 4: softmax stats per b — m = max_p s, z = sum_p exp(s-m)
// grid = B_ blocks, 256 threads
// ---------------------------------------------------------------------------
__global__ __launch_bounds__(256) void softmax_stats_kernel(
    const float* __restrict__ scores, float* __restrict__ mz)
{
    const int b = blockIdx.x;
    const int t = threadIdx.x;
    __shared__ float red[8];

    float m = -1e30f;
    for (int p = t; p < P_; p += 256) m = fmaxf(m, scores[b * P_ + p]);
    #pragma unroll
    for (int d = 1; d < 64; d <<= 1) m = fmaxf(m, __shfl_xor(m, d, 64));
    if ((t & 63) == 0) red[t >> 6] = m;
    __syncthreads();
    if (t == 0) red[4] = fmaxf(fmaxf(red[0], red[1]), fmaxf(red[2], red[3]));
    __syncthreads();
    m = red[4];
    __syncthreads();

    float z = 0.f;
    for (int p = t; p < P_; p += 256) z += expf(scores[b * P_ + p] - m);
    #pragma unroll
    for (int d = 1; d < 64; d <<= 1) z += __shfl_xor(z, d, 64);
    if ((t & 63) == 0) red[t >> 6] = z;
    __syncthreads();
    if (t == 0) { mz[2 * b] = m; mz[2 * b + 1] = red[0] + red[1] + red[2] + red[3]; }
}

// ---------------------------------------------------------------------------
// Kernel 5: weighted partial sums — part[b][sl][q] = sum_{p in slice} e_p * w[b,p,q]
// grid = B_*32 blocks (slice = 128 rows), 256 threads (thread = q)
// ---------------------------------------------------------------------------
__global__ __launch_bounds__(256) void weighted_partial_kernel(
    const float* __restrict__ wmat, const float* __restrict__ scores,
    const float* __restrict__ mz, float* __restrict__ part)
{
    const int blk = blockIdx.x;
    const int b   = blk >> 5;
    const int sl  = blk & 31;
    const int t   = threadIdx.x;
    const float m = mz[2 * b];

    float acc = 0.f;
    const int p0 = sl * 128;
    for (int p = p0; p < p0 + 128; ++p) {
        const float e = expf(scores[b * P_ + p] - m);
        acc += e * wmat[((size_t)b * P_ + p) * WQ_ + t];
    }
    part[(size_t)(b * 32 + sl) * WQ_ + t] = acc;
}

// ---------------------------------------------------------------------------
// Kernel 6: finalize — out[b][q] = (sum_sl part) / z   (deterministic tree)
// grid = B_ blocks, 256 threads
// ---------------------------------------------------------------------------
__global__ __launch_bounds__(256) void finalize_kernel(
    const float* __restrict__ part, const float* __restrict__ mz,
    float* __restrict__ out)
{
    const int b = blockIdx.x;
    const int t = threadIdx.x;
    const float z = mz[2 * b + 1];
    float acc = 0.f;
    #pragma unroll
    for (int sl = 0; sl < 32; ++sl) acc += part[(size_t)(b * 32 + sl) * WQ_ + t];
    out[b * WQ_ + t] = acc / z;
}

// ---------------------------------------------------------------------------
extern "C" void kernel_launch(void* const* d_in, const int* in_sizes, int n_in,
                              void* d_out, int out_size, void* d_ws, size_t ws_size,
                              hipStream_t stream) {
    const float* cx = (const float*)d_in[0];
    const float* gx = (const float*)d_in[1];
    const float* wx = (const float*)d_in[2];
    const float* Wc = (const float*)d_in[3];
    const float* bc = (const float*)d_in[4];
    const float* Wg = (const float*)d_in[5];
    const float* bg = (const float*)d_in[6];
    const float* Ww = (const float*)d_in[7];
    const float* bw = (const float*)d_in[8];
    const float* W1 = (const float*)d_in[9];
    const float* b1 = (const float*)d_in[10];
    const float* W2 = (const float*)d_in[11];
    const float* b2 = (const float*)d_in[12];
    float* out = (float*)d_out;

    // workspace layout (floats)
    float* ws       = (float*)d_ws;
    float* ws_w     = ws;                               // M_*WQ_ = 16,777,216
    float* ws_scores= ws_w + (size_t)M_ * WQ_;          // M_     = 65,536
    float* ws_base  = ws_scores + M_;                   // B_*H_  = 4,096
    float* ws_mz    = ws_base + B_ * H_;                // 2*B_   = 32
    float* ws_part  = ws_mz + 2 * B_;                   // B_*32*WQ_ = 131,072

    prep_kernel<<<B_, 256, 0, stream>>>(cx, gx, Wc, bc, Wg, bg, W1, b1, ws_base);

    gemm_w_kernel<<<M_ / 64, 256, 0, stream>>>(wx, Ww, bw, ws_w);

    gemm_scores_kernel<<<M_ / 64, 256, 0, stream>>>(
        ws_w, W1 + (size_t)(C_ + G_) * H_, ws_base, W2, b2, ws_scores);

    softmax_stats_kernel<<<B_, 256, 0, stream>>>(ws_scores, ws_mz);

    weighted_partial_kernel<<<B_ * 32, 256, 0, stream>>>(ws_w, ws_scores, ws_mz, ws_part);

    finalize_kernel<<<B_, 256, 0, stream>>>(ws_part, ws_mz, out);
}

// Round 2
// 283.983 us; speedup vs baseline: 2.1371x; 2.1371x over previous
//
#include <hip/hip_runtime.h>
#include <hip/hip_bf16.h>

// Problem constants
#define B_   16
#define C_   64
#define G_   256
#define P_   4096
#define W_   1024
#define H_   256
#define WQ_  256
#define M_   (B_ * P_)   // 65536 flattened (b,p) rows

typedef __attribute__((ext_vector_type(8))) short bf16x8;   // MFMA A/B frag (4 VGPRs)
typedef __attribute__((ext_vector_type(4))) float f32x4;    // MFMA C/D frag

// fp32 -> bf16 (RNE) split helpers
__device__ __forceinline__ ushort f2bf(float x) {
    union { float f; unsigned u; } v; v.f = x;
    return (ushort)((v.u + 0x7FFFu + ((v.u >> 16) & 1u)) >> 16);
}
__device__ __forceinline__ float bf2f(ushort h) {
    union { unsigned u; float f; } v; v.u = ((unsigned)h) << 16;
    return v.f;
}
__device__ __forceinline__ void split2(float x, ushort& hi, ushort& lo) {
    hi = f2bf(x);
    lo = f2bf(x - bf2f(hi));
}

// ---------------------------------------------------------------------------
// convT: src[K][N] fp32 -> dh/dl[N][K] bf16 hi/lo planes (transposed)
// grid = (K/64)*(N/64), 256 threads
// ---------------------------------------------------------------------------
__global__ __launch_bounds__(256) void convT_kernel(
    const float* __restrict__ src, ushort* __restrict__ dh,
    ushort* __restrict__ dl, int K, int N)
{
    __shared__ float tile[64][65];
    const int nb = N >> 6;
    const int k0 = (blockIdx.x / nb) * 64;
    const int n0 = (blockIdx.x % nb) * 64;
    const int t = threadIdx.x;
    #pragma unroll
    for (int i = 0; i < 16; ++i) {
        int e = i * 256 + t;
        int kr = e >> 6, nc = e & 63;
        tile[nc][kr] = src[(size_t)(k0 + kr) * N + n0 + nc];
    }
    __syncthreads();
    #pragma unroll
    for (int i = 0; i < 16; ++i) {
        int e = i * 256 + t;
        int nc = e >> 6, kr = e & 63;
        ushort h, l; split2(tile[nc][kr], h, l);
        size_t o = (size_t)(n0 + nc) * K + k0 + kr;
        dh[o] = h; dl[o] = l;
    }
}

// ---------------------------------------------------------------------------
// Kernel 1: prep — c = cx@Wc+bc, g = gx@Wg+bg, base = c@W1c + g@W1g + b1
// ---------------------------------------------------------------------------
__global__ __launch_bounds__(256) void prep_kernel(
    const float* __restrict__ cx, const float* __restrict__ gx,
    const float* __restrict__ Wc, const float* __restrict__ bc,
    const float* __restrict__ Wg, const float* __restrict__ bg,
    const float* __restrict__ W1, const float* __restrict__ b1,
    float* __restrict__ base_out)
{
    const int b = blockIdx.x;
    const int t = threadIdx.x;
    __shared__ float cxl[C_], gxl[G_], cl[C_], gl[G_];

    if (t < C_) cxl[t] = cx[b * C_ + t];
    gxl[t] = gx[b * G_ + t];
    __syncthreads();

    if (t < C_) {
        float acc = bc[t];
        #pragma unroll 4
        for (int i = 0; i < C_; ++i) acc += cxl[i] * Wc[i * C_ + t];
        cl[t] = acc;
    }
    {
        float acc = bg[t];
        #pragma unroll 4
        for (int i = 0; i < G_; ++i) acc += gxl[i] * Wg[i * G_ + t];
        gl[t] = acc;
    }
    __syncthreads();

    float acc = b1[t];
    #pragma unroll 4
    for (int i = 0; i < C_; ++i) acc += cl[i] * W1[i * H_ + t];
    #pragma unroll 4
    for (int i = 0; i < G_; ++i) acc += gl[i] * W1[(C_ + i) * H_ + t];
    base_out[b * H_ + t] = acc;
}

// ---------------------------------------------------------------------------
// Kernel 2: w GEMM via split-bf16 MFMA.
// M=65536,K=1024,N=256. 128x128 tile, BK=32, 4 waves (2x2), 16x16x32 MFMA.
// A (wx fp32) converted to hi/lo bf16 during staging; B pre-converted (BT planes).
// grid = (M/128)*(N/128) = 1024
// ---------------------------------------------------------------------------
__global__ __launch_bounds__(256) void gemm_w_mfma(
    const float* __restrict__ A,      // wx  M x 1024
    const ushort* __restrict__ BTh,   // WwT hi [256][1024]
    const ushort* __restrict__ BTl,   // WwT lo
    const float* __restrict__ bw,
    float* __restrict__ Cout)         // w  M x 256
{
    __shared__ __align__(16) ushort Ah[128 * 32], Al[128 * 32];
    __shared__ __align__(16) ushort Bh[128 * 32], Bl[128 * 32];
    const int t = threadIdx.x;
    const int nblk = blockIdx.x & 1, mblk = blockIdx.x >> 1;
    const int row0 = mblk * 128, col0 = nblk * 128;
    const int lane = t & 63, wave = t >> 6;
    const int wm = wave >> 1, wn = wave & 1;
    const int l15 = lane & 15, lq = lane >> 4;

    // staging coords
    const int s_ar = t >> 3;             // A row base (0..31), +32*i
    const int s_ak = (t & 7) * 4;        // A k offset (floats)
    const int s_bc = t >> 2;             // B col base (0..63), +64*i
    const int s_bk = (t & 3) * 8;        // B k offset (ushorts)

    f32x4 acc[4][4];
    #pragma unroll
    for (int m = 0; m < 4; ++m)
        #pragma unroll
        for (int n = 0; n < 4; ++n) acc[m][n] = (f32x4){0.f, 0.f, 0.f, 0.f};

    for (int k0 = 0; k0 < W_; k0 += 32) {
        // stage A (fp32 -> hi/lo bf16, swizzled)
        #pragma unroll
        for (int i = 0; i < 4; ++i) {
            const int r = s_ar + 32 * i;
            const float4 v = *(const float4*)(A + (size_t)(row0 + r) * W_ + k0 + s_ak);
            ushort4 hv, lv;
            split2(v.x, hv.x, lv.x); split2(v.y, hv.y, lv.y);
            split2(v.z, hv.z, lv.z); split2(v.w, hv.w, lv.w);
            const int byte = (r * 64 + s_ak * 2) ^ ((r & 7) << 4);
            *(ushort4*)((char*)Ah + byte) = hv;
            *(ushort4*)((char*)Al + byte) = lv;
        }
        // stage B (already bf16, swizzled)
        #pragma unroll
        for (int i = 0; i < 2; ++i) {
            const int c = s_bc + 64 * i;
            const int byte = (c * 64 + s_bk * 2) ^ ((c & 7) << 4);
            *(uint4*)((char*)Bh + byte) =
                *(const uint4*)(BTh + (size_t)(col0 + c) * W_ + k0 + s_bk);
            *(uint4*)((char*)Bl + byte) =
                *(const uint4*)(BTl + (size_t)(col0 + c) * W_ + k0 + s_bk);
        }
        __syncthreads();

        bf16x8 afh[4], afl[4], bfh[4], bfl[4];
        #pragma unroll
        for (int m = 0; m < 4; ++m) {
            const int r = wm * 64 + m * 16 + l15;
            const int byte = (r * 64 + lq * 16) ^ ((r & 7) << 4);
            afh[m] = *(const bf16x8*)((const char*)Ah + byte);
            afl[m] = *(const bf16x8*)((const char*)Al + byte);
        }
        #pragma unroll
        for (int n = 0; n < 4; ++n) {
            const int c = wn * 64 + n * 16 + l15;
            const int byte = (c * 64 + lq * 16) ^ ((c & 7) << 4);
            bfh[n] = *(const bf16x8*)((const char*)Bh + byte);
            bfl[n] = *(const bf16x8*)((const char*)Bl + byte);
        }
        #pragma unroll
        for (int m = 0; m < 4; ++m)
            #pragma unroll
            for (int n = 0; n < 4; ++n) {
                acc[m][n] = __builtin_amdgcn_mfma_f32_16x16x32_bf16(afh[m], bfh[n], acc[m][n], 0, 0, 0);
                acc[m][n] = __builtin_amdgcn_mfma_f32_16x16x32_bf16(afh[m], bfl[n], acc[m][n], 0, 0, 0);
                acc[m][n] = __builtin_amdgcn_mfma_f32_16x16x32_bf16(afl[m], bfh[n], acc[m][n], 0, 0, 0);
            }
        __syncthreads();
    }

    // epilogue: C[row][col] = acc + bw[col]
    float bwv[4];
    #pragma unroll
    for (int n = 0; n < 4; ++n) bwv[n] = bw[col0 + wn * 64 + n * 16 + l15];
    #pragma unroll
    for (int m = 0; m < 4; ++m)
        #pragma unroll
        for (int reg = 0; reg < 4; ++reg) {
            const size_t r = (size_t)row0 + wm * 64 + m * 16 + lq * 4 + reg;
            #pragma unroll
            for (int n = 0; n < 4; ++n)
                Cout[r * WQ_ + col0 + wn * 64 + n * 16 + l15] = acc[m][n][reg] + bwv[n];
        }
}

// ---------------------------------------------------------------------------
// Kernel 3: scores via split-bf16 MFMA + fused relu/dot(W2) epilogue.
// M=65536,K=256(q),N=256(h). BM=64, BN=256, 4 waves (1x4 over N), BK=32.
// grid = M/64 = 1024
// ---------------------------------------------------------------------------
__global__ __launch_bounds__(256) void gemm_scores_mfma(
    const float* __restrict__ A,      // w M x 256
    const ushort* __restrict__ BTh,   // W1wT hi [256][256]
    const ushort* __restrict__ BTl,
    const float* __restrict__ base_,  // B_ x 256
    const float* __restrict__ W2,     // 256
    const float* __restrict__ b2,     // 1
    float* __restrict__ scores)       // M
{
    __shared__ __align__(16) ushort Ah[64 * 32], Al[64 * 32];
    __shared__ __align__(16) ushort Bh[256 * 32], Bl[256 * 32];
    __shared__ float red[4][64];
    const int t = threadIdx.x;
    const int row0 = blockIdx.x * 64;
    const int b = blockIdx.x >> 6;            // 4096/64 blocks per batch
    const int lane = t & 63, wave = t >> 6;   // wave = 64-col strip of H
    const int l15 = lane & 15, lq = lane >> 4;

    const int s_ar = t >> 3;
    const int s_ak = (t & 7) * 4;
    const int s_bc = t >> 2;
    const int s_bk = (t & 3) * 8;

    f32x4 acc[4][4];
    #pragma unroll
    for (int m = 0; m < 4; ++m)
        #pragma unroll
        for (int n = 0; n < 4; ++n) acc[m][n] = (f32x4){0.f, 0.f, 0.f, 0.f};

    for (int k0 = 0; k0 < H_; k0 += 32) {
        #pragma unroll
        for (int i = 0; i < 2; ++i) {
            const int r = s_ar + 32 * i;
            const float4 v = *(const float4*)(A + (size_t)(row0 + r) * H_ + k0 + s_ak);
            ushort4 hv, lv;
            split2(v.x, hv.x, lv.x); split2(v.y, hv.y, lv.y);
            split2(v.z, hv.z, lv.z); split2(v.w, hv.w, lv.w);
            const int byte = (r * 64 + s_ak * 2) ^ ((r & 7) << 4);
            *(ushort4*)((char*)Ah + byte) = hv;
            *(ushort4*)((char*)Al + byte) = lv;
        }
        #pragma unroll
        for (int i = 0; i < 4; ++i) {
            const int c = s_bc + 64 * i;
            const int byte = (c * 64 + s_bk * 2) ^ ((c & 7) << 4);
            *(uint4*)((char*)Bh + byte) = *(const uint4*)(BTh + (size_t)c * H_ + k0 + s_bk);
            *(uint4*)((char*)Bl + byte) = *(const uint4*)(BTl + (size_t)c * H_ + k0 + s_bk);
        }
        __syncthreads();

        bf16x8 afh[4], afl[4], bfh[4], bfl[4];
        #pragma unroll
        for (int m = 0; m < 4; ++m) {
            const int r = m * 16 + l15;
            const int byte = (r * 64 + lq * 16) ^ ((r & 7) << 4);
            afh[m] = *(const bf16x8*)((const char*)Ah + byte);
            afl[m] = *(const bf16x8*)((const char*)Al + byte);
        }
        #pragma unroll
        for (int n = 0; n < 4; ++n) {
            const int c = wave * 64 + n * 16 + l15;
            const int byte = (c * 64 + lq * 16) ^ ((c & 7) << 4);
            bfh[n] = *(const bf16x8*)((const char*)Bh + byte);
            bfl[n] = *(const bf16x8*)((const char*)Bl + byte);
        }
        #pragma unroll
        for (int m = 0; m < 4; ++m)
            #pragma unroll
            for (int n = 0; n < 4; ++n) {
                acc[m][n] = __builtin_amdgcn_mfma_f32_16x16x32_bf16(afh[m], bfh[n], acc[m][n], 0, 0, 0);
                acc[m][n] = __builtin_amdgcn_mfma_f32_16x16x32_bf16(afh[m], bfl[n], acc[m][n], 0, 0, 0);
                acc[m][n] = __builtin_amdgcn_mfma_f32_16x16x32_bf16(afl[m], bfh[n], acc[m][n], 0, 0, 0);
            }
        __syncthreads();
    }

    // epilogue: scores[row] = sum_h relu(acc + base) * W2  (+ b2)
    float basev[4], w2v[4];
    #pragma unroll
    for (int n = 0; n < 4; ++n) {
        const int col = wave * 64 + n * 16 + l15;
        basev[n] = base_[b * H_ + col];
        w2v[n] = W2[col];
    }
    #pragma unroll
    for (int m = 0; m < 4; ++m)
        #pragma unroll
        for (int reg = 0; reg < 4; ++reg) {
            float s = 0.f;
            #pragma unroll
            for (int n = 0; n < 4; ++n) {
                float h = acc[m][n][reg] + basev[n];
                h = fmaxf(h, 0.f);
                s += h * w2v[n];
            }
            // reduce over the 16 cols held by lanes sharing lq
            s += __shfl_xor(s, 1, 64);
            s += __shfl_xor(s, 2, 64);
            s += __shfl_xor(s, 4, 64);
            s += __shfl_xor(s, 8, 64);
            if (l15 == 0) red[wave][m * 16 + lq * 4 + reg] = s;
        }
    __syncthreads();
    if (t < 64) {
        scores[row0 + t] = red[0][t] + red[1][t] + red[2][t] + red[3][t] + b2[0];
    }
}

// ---------------------------------------------------------------------------
// Kernel 4: softmax stats per b — m = max_p s, z = sum_p exp(s-m)
// ---------------------------------------------------------------------------
__global__ __launch_bounds__(256) void softmax_stats_kernel(
    const float* __restrict__ scores, float* __restrict__ mz)
{
    const int b = blockIdx.x;
    const int t = threadIdx.x;
    __shared__ float red[8];

    float m = -1e30f;
    for (int p = t; p < P_; p += 256) m = fmaxf(m, scores[b * P_ + p]);
    #pragma unroll
    for (int d = 1; d < 64; d <<= 1) m = fmaxf(m, __shfl_xor(m, d, 64));
    if ((t & 63) == 0) red[t >> 6] = m;
    __syncthreads();
    if (t == 0) red[4] = fmaxf(fmaxf(red[0], red[1]), fmaxf(red[2], red[3]));
    __syncthreads();
    m = red[4];
    __syncthreads();

    float z = 0.f;
    for (int p = t; p < P_; p += 256) z += expf(scores[b * P_ + p] - m);
    #pragma unroll
    for (int d = 1; d < 64; d <<= 1) z += __shfl_xor(z, d, 64);
    if ((t & 63) == 0) red[t >> 6] = z;
    __syncthreads();
    if (t == 0) { mz[2 * b] = m; mz[2 * b + 1] = red[0] + red[1] + red[2] + red[3]; }
}

// ---------------------------------------------------------------------------
// Kernel 5: weighted partial sums over 128-row slices
// ---------------------------------------------------------------------------
__global__ __launch_bounds__(256) void weighted_partial_kernel(
    const float* __restrict__ wmat, const float* __restrict__ scores,
    const float* __restrict__ mz, float* __restrict__ part)
{
    const int blk = blockIdx.x;
    const int b   = blk >> 5;
    const int sl  = blk & 31;
    const int t   = threadIdx.x;
    const float m = mz[2 * b];

    float acc = 0.f;
    const int p0 = sl * 128;
    for (int p = p0; p < p0 + 128; ++p) {
        const float e = expf(scores[b * P_ + p] - m);
        acc += e * wmat[((size_t)b * P_ + p) * WQ_ + t];
    }
    part[(size_t)(b * 32 + sl) * WQ_ + t] = acc;
}

// ---------------------------------------------------------------------------
// Kernel 6: finalize
// ---------------------------------------------------------------------------
__global__ __launch_bounds__(256) void finalize_kernel(
    const float* __restrict__ part, const float* __restrict__ mz,
    float* __restrict__ out)
{
    const int b = blockIdx.x;
    const int t = threadIdx.x;
    const float z = mz[2 * b + 1];
    float acc = 0.f;
    #pragma unroll
    for (int sl = 0; sl < 32; ++sl) acc += part[(size_t)(b * 32 + sl) * WQ_ + t];
    out[b * WQ_ + t] = acc / z;
}

// ---------------------------------------------------------------------------
extern "C" void kernel_launch(void* const* d_in, const int* in_sizes, int n_in,
                              void* d_out, int out_size, void* d_ws, size_t ws_size,
                              hipStream_t stream) {
    const float* cx = (const float*)d_in[0];
    const float* gx = (const float*)d_in[1];
    const float* wx = (const float*)d_in[2];
    const float* Wc = (const float*)d_in[3];
    const float* bc = (const float*)d_in[4];
    const float* Wg = (const float*)d_in[5];
    const float* bg = (const float*)d_in[6];
    const float* Ww = (const float*)d_in[7];
    const float* bw = (const float*)d_in[8];
    const float* W1 = (const float*)d_in[9];
    const float* b1 = (const float*)d_in[10];
    const float* W2 = (const float*)d_in[11];
    const float* b2 = (const float*)d_in[12];
    float* out = (float*)d_out;

    // workspace layout
    float* ws        = (float*)d_ws;
    float* ws_w      = ws;                               // M_*WQ_
    float* ws_scores = ws_w + (size_t)M_ * WQ_;          // M_
    float* ws_base   = ws_scores + M_;                   // B_*H_
    float* ws_mz     = ws_base + B_ * H_;                // 2*B_
    float* ws_part   = ws_mz + 2 * B_;                   // B_*32*WQ_
    ushort* WwTh     = (ushort*)(ws_part + B_ * 32 * WQ_);
    ushort* WwTl     = WwTh + (size_t)W_ * WQ_;
    ushort* W1Th     = WwTl + (size_t)W_ * WQ_;
    ushort* W1Tl     = W1Th + (size_t)H_ * H_;

    // one-time weight transpose+convert (cheap; runs every call for determinism)
    convT_kernel<<<(W_ / 64) * (WQ_ / 64), 256, 0, stream>>>(Ww, WwTh, WwTl, W_, WQ_);
    convT_kernel<<<(H_ / 64) * (H_ / 64), 256, 0, stream>>>(
        W1 + (size_t)(C_ + G_) * H_, W1Th, W1Tl, H_, H_);

    prep_kernel<<<B_, 256, 0, stream>>>(cx, gx, Wc, bc, Wg, bg, W1, b1, ws_base);

    gemm_w_mfma<<<(M_ / 128) * (WQ_ / 128), 256, 0, stream>>>(wx, WwTh, WwTl, bw, ws_w);

    gemm_scores_mfma<<<M_ / 64, 256, 0, stream>>>(
        ws_w, W1Th, W1Tl, ws_base, W2, b2, ws_scores);

    softmax_stats_kernel<<<B_, 256, 0, stream>>>(ws_scores, ws_mz);

    weighted_partial_kernel<<<B_ * 32, 256, 0, stream>>>(ws_w, ws_scores, ws_mz, ws_part);

    finalize_kernel<<<B_, 256, 0, stream>>>(ws_part, ws_mz, out);
}